// Round 1
// baseline (50.949 us; speedup 1.0000x reference)
//
#include <hip/hip_runtime.h>
#include <math.h>

#define NN 16384
#define DD 1024
#define HD 512

// ws layout (float units):
// [0]                : (int)  dynamic_k
// [4..14)            : (int)  neighbor_idx[10]
// [16..26)           : float  scores[10]
// [32 .. 32+11*1024) : float  uv[11][1024]   k=0..9 -> v_k, k=10 -> u (x @ W_att1_top)
// [11296 .. +16*512) : float  hp[16][512]    cnt-MLP hidden partials
#define WS_DK  0
#define WS_NB  4
#define WS_SC  16
#define WS_UV  32
#define WS_HP  11296

// ---------- kernel 1: cnt-MLP hidden partials (deterministic two-phase) ----------
__global__ void k_cnt_partial(const float* __restrict__ x, const float* __restrict__ Wc1,
                              float* __restrict__ ws) {
    __shared__ float xs[64];
    const int t = threadIdx.x;          // 512
    const int ib = blockIdx.x;          // 16 blocks, 64 i's each
    const int ibase = ib * 64;
    if (t < 64) xs[t] = x[ibase + t];
    __syncthreads();
    float acc = 0.f;
    const float* W = Wc1 + (size_t)ibase * HD + t;
    #pragma unroll 8
    for (int ii = 0; ii < 64; ++ii) acc += xs[ii] * W[(size_t)ii * HD];
    ws[WS_HP + ib * HD + t] = acc;
}

// ---------- kernel 2: cnt-MLP finish -> dynamic_k (deterministic) ----------
__global__ void k_cnt_final(const float* __restrict__ bc1, const float* __restrict__ Wc2,
                            const float* __restrict__ bc2, float* __restrict__ ws) {
    __shared__ float red[512];
    const int t = threadIdx.x;          // 512
    float s = 0.f;
    #pragma unroll
    for (int ib = 0; ib < 16; ++ib) s += ws[WS_HP + ib * HD + t];
    float h = fmaxf(s + bc1[t], 0.f);
    red[t] = h * Wc2[t];
    __syncthreads();
    for (int off = 256; off > 0; off >>= 1) {
        if (t < off) red[t] += red[t + off];
        __syncthreads();
    }
    if (t == 0) {
        float z = red[0] + bc2[0];
        float frac = 1.f / (1.f + expf(-z));
        int dk = (int)floorf(frac * 10.f);
        dk = dk < 1 ? 1 : (dk > 10 ? 10 : dk);
        ((int*)ws)[WS_DK] = dk;
    }
}

// ---------- kernel 3: top-11 over the target row + stable compaction ----------
// Also zeroes the uv accumulator region (runs before k_att_gemm on the stream).
__global__ void k_topk(const float* __restrict__ sim, const int* __restrict__ tidx,
                       float* __restrict__ ws, float* __restrict__ out) {
    const int t = threadIdx.x;          // 512
    for (int i = t; i < 11 * DD; i += 512) ws[WS_UV + i] = 0.f;

    const int tgt = tidx[0];
    const float* row = sim + (size_t)tgt * NN;
    float vals[32];
    #pragma unroll
    for (int s = 0; s < 32; ++s) vals[s] = row[t + s * 512];
    unsigned used = 0u;

    __shared__ float wvs[8];
    __shared__ int   wgs[8];
    __shared__ int   winner;
    __shared__ int   toplist[11];
    const int lane = t & 63, wave = t >> 6;

    for (int it = 0; it < 11; ++it) {
        // local argmax over 32 register-resident values (ties -> smaller s = smaller idx)
        float bv = -INFINITY; int bs = 0;
        #pragma unroll
        for (int s = 0; s < 32; ++s) {
            float v = ((used >> s) & 1u) ? -INFINITY : vals[s];
            if (v > bv) { bv = v; bs = s; }
        }
        int gi = t + bs * 512;
        // wave reduce (larger val, tie -> smaller global idx)
        for (int off = 32; off > 0; off >>= 1) {
            float ov = __shfl_down(bv, off);
            int   og = __shfl_down(gi, off);
            if (ov > bv || (ov == bv && og < gi)) { bv = ov; gi = og; }
        }
        if (lane == 0) { wvs[wave] = bv; wgs[wave] = gi; }
        __syncthreads();
        if (t == 0) {
            float fv = wvs[0]; int fg = wgs[0];
            for (int w = 1; w < 8; ++w)
                if (wvs[w] > fv || (wvs[w] == fv && wgs[w] < fg)) { fv = wvs[w]; fg = wgs[w]; }
            toplist[it] = fg;
            winner = fg;
        }
        __syncthreads();
        int w = winner;
        if ((w & 511) == t) used |= 1u << (w >> 9);
        // next write to winner happens only after another __syncthreads -> safe
    }
    if (t == 0) {
        // stable compaction: drop target_idx if present, else drop the 11th
        int cnt = 0;
        int* nb = (int*)ws + WS_NB;
        for (int i = 0; i < 11 && cnt < 10; ++i) {
            int v = toplist[i];
            if (v != tgt) { nb[cnt] = v; out[1034 + cnt] = (float)v; ++cnt; }
        }
    }
}

// ---------- kernel 4: attention GEMM  uv[k][j] += emb_k . W_att1_bot[:,j] (k=10: x . W_att1_top) ----------
__global__ void k_att_gemm(const float* __restrict__ x, const float* __restrict__ emb,
                           const float* __restrict__ W1, float* __restrict__ ws) {
    __shared__ float xs[64];
    __shared__ float es[10][64];
    __shared__ int   nb[10];
    const int t = threadIdx.x;              // 256
    const int jc = blockIdx.x & 3;          // 4 j-chunks of 256
    const int ic = blockIdx.x >> 2;         // 16 i-chunks of 64
    const int ibase = ic * 64;
    const int j = jc * 256 + t;
    if (t < 10) nb[t] = ((const int*)ws)[WS_NB + t];
    if (t < 64) xs[t] = x[ibase + t];
    __syncthreads();
    for (int idx = t; idx < 640; idx += 256) {
        int k = idx >> 6, ii = idx & 63;
        es[k][ii] = emb[(size_t)nb[k] * DD + ibase + ii];
    }
    __syncthreads();
    float acc[11];
    #pragma unroll
    for (int k = 0; k < 11; ++k) acc[k] = 0.f;
    const float* Wt = W1 + (size_t)ibase * DD + j;
    const float* Wb = W1 + (size_t)(1024 + ibase) * DD + j;
    for (int ii = 0; ii < 64; ++ii) {
        float wt = Wt[(size_t)ii * DD];
        float wb = Wb[(size_t)ii * DD];
        acc[10] += xs[ii] * wt;
        #pragma unroll
        for (int k = 0; k < 10; ++k) acc[k] += es[k][ii] * wb;
    }
    #pragma unroll
    for (int k = 0; k < 11; ++k) atomicAdd(&ws[WS_UV + k * DD + j], acc[k]);
}

// ---------- kernel 5: scores[k] = relu(u + v_k + b1) . W2 + b2 ----------
__global__ void k_att_score(const float* __restrict__ ba1, const float* __restrict__ W2,
                            const float* __restrict__ ba2, float* __restrict__ ws) {
    __shared__ float red[256];
    const int t = threadIdx.x;   // 256
    const int k = blockIdx.x;    // 10
    float acc = 0.f;
    #pragma unroll
    for (int jj = 0; jj < 4; ++jj) {
        int j = jj * 256 + t;
        float h = ws[WS_UV + 10 * DD + j] + ws[WS_UV + k * DD + j] + ba1[j];
        h = fmaxf(h, 0.f);
        acc += h * W2[j];
    }
    red[t] = acc;
    __syncthreads();
    for (int off = 128; off > 0; off >>= 1) {
        if (t < off) red[t] += red[t + off];
        __syncthreads();
    }
    if (t == 0) ws[WS_SC + k] = red[0] + ba2[0];
}

// ---------- kernel 6: mask + softmax + weighted aggregate + write outputs ----------
__global__ void k_final(const float* __restrict__ emb, float* __restrict__ ws,
                        float* __restrict__ out) {
    __shared__ float wl[10];
    __shared__ int   nbs[10];
    const int t = threadIdx.x;  // 1024
    if (t == 0) {
        int dk = ((const int*)ws)[WS_DK];
        float sc[10];
        float m = -INFINITY;
        for (int k = 0; k < 10; ++k) {
            float s = ws[WS_SC + k];
            sc[k] = (k < dk) ? s : -INFINITY;
            if (sc[k] > m) m = sc[k];
        }
        float sum = 0.f;
        for (int k = 0; k < 10; ++k) { sc[k] = expf(sc[k] - m); sum += sc[k]; }
        for (int k = 0; k < 10; ++k) wl[k] = sc[k] / sum;
    }
    if (t < 10) nbs[t] = ((const int*)ws)[WS_NB + t];
    __syncthreads();
    float a = 0.f;
    #pragma unroll
    for (int k = 0; k < 10; ++k) a += wl[k] * emb[(size_t)nbs[k] * DD + t];
    out[t] = a;
    if (t < 10) { out[1024 + t] = wl[t]; out[1044 + t] = wl[t]; }
}

extern "C" void kernel_launch(void* const* d_in, const int* in_sizes, int n_in,
                              void* d_out, int out_size, void* d_ws, size_t ws_size,
                              hipStream_t stream) {
    const float* x    = (const float*)d_in[0];   // target_embedding [1024]
    const float* emb  = (const float*)d_in[1];   // all_embeddings [16384,1024]
    const float* sim  = (const float*)d_in[2];   // similarity_matrix [16384,16384]
    const float* W1   = (const float*)d_in[3];   // W_att1 [2048,1024]
    const float* ba1  = (const float*)d_in[4];   // b_att1 [1024]
    const float* W2   = (const float*)d_in[5];   // W_att2 [1024]
    const float* ba2  = (const float*)d_in[6];   // b_att2 [1]
    const float* Wc1  = (const float*)d_in[7];   // W_cnt1 [1024,512]
    const float* bc1  = (const float*)d_in[8];   // b_cnt1 [512]
    const float* Wc2  = (const float*)d_in[9];   // W_cnt2 [512]
    const float* bc2  = (const float*)d_in[10];  // b_cnt2 [1]
    const int*   tidx = (const int*)d_in[11];    // target_idx [1]
    float* out = (float*)d_out;
    float* ws  = (float*)d_ws;

    hipLaunchKernelGGL(k_cnt_partial, dim3(16), dim3(512), 0, stream, x, Wc1, ws);
    hipLaunchKernelGGL(k_cnt_final,   dim3(1),  dim3(512), 0, stream, bc1, Wc2, bc2, ws);
    hipLaunchKernelGGL(k_topk,        dim3(1),  dim3(512), 0, stream, sim, tidx, ws, out);
    hipLaunchKernelGGL(k_att_gemm,    dim3(64), dim3(256), 0, stream, x, emb, W1, ws);
    hipLaunchKernelGGL(k_att_score,   dim3(10), dim3(256), 0, stream, ba1, W2, ba2, ws);
    hipLaunchKernelGGL(k_final,       dim3(1),  dim3(1024), 0, stream, emb, ws, out);
}

// Round 2
// 38.355 us; speedup vs baseline: 1.3284x; 1.3284x over previous
//
#include <hip/hip_runtime.h>
#include <math.h>

#define NN 16384
#define DD 1024
#define HD 512

// ws layout (float units):
// [0]                 : (int)  dynamic_k
// [4..14)             : (int)  neighbor_idx[10]
// [32 .. 32+11*1024)  : float  uv[11][1024]   k=0..9 -> v_k, k=10 -> u (x @ W_att1_top)
// [11296 .. +32*512)  : float  hp[32][512]    cnt-MLP hidden partials
#define WS_DK  0
#define WS_NB  4
#define WS_UV  32
#define WS_HP  11296

// ---------- phase A: block 0 = top-11 + zero uv; blocks 1..32 = cnt-MLP partials ----------
__global__ void k_phaseA(const float* __restrict__ x, const float* __restrict__ Wc1,
                         const float* __restrict__ sim, const int* __restrict__ tidx,
                         float* __restrict__ ws, float* __restrict__ out) {
    const int t = threadIdx.x;              // 512
    const int b = blockIdx.x;               // 0..32
    if (b != 0) {
        // cnt partial: chunk c covers 32 input rows, 512 output j's (1 per thread)
        __shared__ float xs[32];
        const int c = b - 1;
        const int ibase = c * 32;
        if (t < 32) xs[t] = x[ibase + t];
        __syncthreads();
        float acc = 0.f;
        const float* W = Wc1 + (size_t)ibase * HD + t;
        #pragma unroll 8
        for (int ii = 0; ii < 32; ++ii) acc += xs[ii] * W[(size_t)ii * HD];
        ws[WS_HP + c * HD + t] = acc;
        return;
    }

    // ---- block 0: zero uv accumulators (consumed by phase B's atomics) ----
    for (int i = t; i < 11 * DD; i += 512) ws[WS_UV + i] = 0.f;

    // ---- top-11 over the target's similarity row ----
    const int tgt = tidx[0];
    const float4* row4 = (const float4*)(sim + (size_t)tgt * NN);
    float vals[32];
    #pragma unroll
    for (int c = 0; c < 8; ++c) {
        float4 v = row4[c * 512 + t];
        vals[c * 4 + 0] = v.x; vals[c * 4 + 1] = v.y;
        vals[c * 4 + 2] = v.z; vals[c * 4 + 3] = v.w;
    }
    // global index of vals[s=c*4+q] is gi = c*2048 + t*4 + q (monotone in s for fixed t)
    unsigned used = 0u;

    __shared__ float wvs[8];
    __shared__ int   wgs[8];
    __shared__ int   winner;
    __shared__ int   toplist[11];
    const int lane = t & 63, wave = t >> 6;

    for (int it = 0; it < 11; ++it) {
        float bv = -INFINITY; int bs = 0;
        #pragma unroll
        for (int s = 0; s < 32; ++s) {
            float v = ((used >> s) & 1u) ? -INFINITY : vals[s];
            if (v > bv) { bv = v; bs = s; }   // strict > keeps earliest s = smallest gi
        }
        int gi = (bs >> 2) * 2048 + t * 4 + (bs & 3);
        // wave reduce: larger val, tie -> smaller global idx
        for (int off = 32; off > 0; off >>= 1) {
            float ov = __shfl_down(bv, off);
            int   og = __shfl_down(gi, off);
            if (ov > bv || (ov == bv && og < gi)) { bv = ov; gi = og; }
        }
        if (lane == 0) { wvs[wave] = bv; wgs[wave] = gi; }
        __syncthreads();
        if (t == 0) {
            float fv = wvs[0]; int fg = wgs[0];
            for (int w = 1; w < 8; ++w)
                if (wvs[w] > fv || (wvs[w] == fv && wgs[w] < fg)) { fv = wvs[w]; fg = wgs[w]; }
            toplist[it] = fg;
            winner = fg;
        }
        __syncthreads();
        int w = winner;
        if (((w >> 2) & 511) == t) used |= 1u << ((w >> 11) * 4 + (w & 3));
    }
    if (t == 0) {
        // stable compaction: drop target_idx if present, else drop the 11th
        int cnt = 0;
        int* nb = (int*)ws + WS_NB;
        for (int i = 0; i < 11 && cnt < 10; ++i) {
            int v = toplist[i];
            if (v != tgt) { nb[cnt] = v; out[1034 + cnt] = (float)v; ++cnt; }
        }
    }
}

// ---------- phase B: blocks 0..127 = attention GEMM; block 128 = cnt-MLP finish ----------
__global__ void k_phaseB(const float* __restrict__ x, const float* __restrict__ emb,
                         const float* __restrict__ W1, const float* __restrict__ bc1,
                         const float* __restrict__ Wc2, const float* __restrict__ bc2,
                         float* __restrict__ ws) {
    const int t = threadIdx.x;              // 256
    const int b = blockIdx.x;               // 0..128
    if (b == 128) {
        // cnt-MLP finish -> dynamic_k (deterministic fixed-order sums)
        __shared__ float red[256];
        float acc = 0.f;
        #pragma unroll
        for (int jj = 0; jj < 2; ++jj) {
            int j = t + jj * 256;
            float s = 0.f;
            #pragma unroll 8
            for (int c = 0; c < 32; ++c) s += ws[WS_HP + c * HD + j];
            float h = fmaxf(s + bc1[j], 0.f);
            acc += h * Wc2[j];
        }
        red[t] = acc;
        __syncthreads();
        for (int off = 128; off > 0; off >>= 1) {
            if (t < off) red[t] += red[t + off];
            __syncthreads();
        }
        if (t == 0) {
            float z = red[0] + bc2[0];
            float frac = 1.f / (1.f + expf(-z));
            int dk = (int)floorf(frac * 10.f);
            ((int*)ws)[WS_DK] = dk < 1 ? 1 : (dk > 10 ? 10 : dk);
        }
        return;
    }
    // attention GEMM: uv[k][j] += emb_k[i-chunk] . W1_bot[i-chunk, j]  (k=10: x . W1_top)
    __shared__ float xs[32];
    __shared__ float es[10][32];
    __shared__ int   nb[10];
    const int jc = b & 3;                   // 4 j-chunks of 256
    const int ic = b >> 2;                  // 32 i-chunks of 32
    const int ibase = ic * 32;
    const int j = jc * 256 + t;
    if (t < 10) nb[t] = ((const int*)ws)[WS_NB + t];
    if (t < 32) xs[t] = x[ibase + t];
    __syncthreads();
    for (int idx = t; idx < 320; idx += 256) {
        int k = idx >> 5, ii = idx & 31;
        es[k][ii] = emb[(size_t)nb[k] * DD + ibase + ii];
    }
    __syncthreads();
    float acc[11];
    #pragma unroll
    for (int k = 0; k < 11; ++k) acc[k] = 0.f;
    const float* Wt = W1 + (size_t)ibase * DD + j;
    const float* Wb = W1 + (size_t)(1024 + ibase) * DD + j;
    for (int ii = 0; ii < 32; ++ii) {
        float wt = Wt[(size_t)ii * DD];
        float wb = Wb[(size_t)ii * DD];
        acc[10] += xs[ii] * wt;
        #pragma unroll
        for (int k = 0; k < 10; ++k) acc[k] += es[k][ii] * wb;
    }
    #pragma unroll
    for (int k = 0; k < 11; ++k) atomicAdd(&ws[WS_UV + k * DD + j], acc[k]);
}

// ---------- phase C: scores (1 wave per k) + softmax + aggregate + outputs ----------
__global__ void k_phaseC(const float* __restrict__ emb, const float* __restrict__ ba1,
                         const float* __restrict__ W2, const float* __restrict__ ba2,
                         float* __restrict__ ws, float* __restrict__ out) {
    const int t = threadIdx.x;              // 1024
    const int wave = t >> 6, lane = t & 63;
    __shared__ float sc[10];
    __shared__ float wl[10];
    __shared__ int   nbs[10];
    if (t < 10) nbs[t] = ((const int*)ws)[WS_NB + t];
    if (wave < 10) {
        float acc = 0.f;
        #pragma unroll
        for (int m = 0; m < 16; ++m) {
            int j = lane + m * 64;
            float h = ws[WS_UV + 10 * DD + j] + ws[WS_UV + wave * DD + j] + ba1[j];
            acc += fmaxf(h, 0.f) * W2[j];
        }
        #pragma unroll
        for (int off = 32; off > 0; off >>= 1) acc += __shfl_down(acc, off);
        if (lane == 0) sc[wave] = acc + ba2[0];
    }
    __syncthreads();
    if (t == 0) {
        int dk = ((const int*)ws)[WS_DK];
        float v[10];
        float m = -INFINITY;
        for (int k = 0; k < 10; ++k) {
            v[k] = (k < dk) ? sc[k] : -INFINITY;
            if (v[k] > m) m = v[k];
        }
        float sum = 0.f;
        for (int k = 0; k < 10; ++k) { v[k] = expf(v[k] - m); sum += v[k]; }
        for (int k = 0; k < 10; ++k) wl[k] = v[k] / sum;
    }
    __syncthreads();
    float a = 0.f;
    #pragma unroll
    for (int k = 0; k < 10; ++k) a += wl[k] * emb[(size_t)nbs[k] * DD + t];
    out[t] = a;
    if (t < 10) { out[1024 + t] = wl[t]; out[1044 + t] = wl[t]; }
}

extern "C" void kernel_launch(void* const* d_in, const int* in_sizes, int n_in,
                              void* d_out, int out_size, void* d_ws, size_t ws_size,
                              hipStream_t stream) {
    const float* x    = (const float*)d_in[0];   // target_embedding [1024]
    const float* emb  = (const float*)d_in[1];   // all_embeddings [16384,1024]
    const float* sim  = (const float*)d_in[2];   // similarity_matrix [16384,16384]
    const float* W1   = (const float*)d_in[3];   // W_att1 [2048,1024]
    const float* ba1  = (const float*)d_in[4];   // b_att1 [1024]
    const float* W2   = (const float*)d_in[5];   // W_att2 [1024]
    const float* ba2  = (const float*)d_in[6];   // b_att2 [1]
    const float* Wc1  = (const float*)d_in[7];   // W_cnt1 [1024,512]
    const float* bc1  = (const float*)d_in[8];   // b_cnt1 [512]
    const float* Wc2  = (const float*)d_in[9];   // W_cnt2 [512]
    const float* bc2  = (const float*)d_in[10];  // b_cnt2 [1]
    const int*   tidx = (const int*)d_in[11];    // target_idx [1]
    float* out = (float*)d_out;
    float* ws  = (float*)d_ws;

    hipLaunchKernelGGL(k_phaseA, dim3(33),  dim3(512),  0, stream, x, Wc1, sim, tidx, ws, out);
    hipLaunchKernelGGL(k_phaseB, dim3(129), dim3(256),  0, stream, x, emb, W1, bc1, Wc2, bc2, ws);
    hipLaunchKernelGGL(k_phaseC, dim3(1),   dim3(1024), 0, stream, emb, ba1, W2, ba2, ws, out);
}